// Round 1
// baseline (663.424 us; speedup 1.0000x reference)
//
#include <hip/hip_runtime.h>

#define M_DIM 1024
#define N_DIM 100000
#define K_DIM 64
#define HIST 50

#define BM 64
#define BN 128
#define BMP 68    // selT k-major row stride ([K][BMP]), 68*4 B = 272 B (16B aligned)
#define BNP 132   // itemT k-major row stride ([K][BNP]), 132*4 B = 528 B (16B aligned)

#define SEL_OFF 0
#define ITEM_OFF (K_DIM * BMP)                 // 4352 floats
#define LDS_FLOATS (K_DIM * BMP + K_DIM * BNP) // 12800 floats = 51200 B

// GEMM + sum(s^2): block = 256 threads, tile = 64 rows x 128 items, full K=64.
// Thread micro-tile: 8 rows x 4 items (items interleaved stride 32 for
// conflict-free LDS b-reads and contiguous-lane global stores).
__global__ __launch_bounds__(256, 3) void gemm_loss_kernel(
    const float* __restrict__ user_emb, const float* __restrict__ item_emb,
    const int* __restrict__ center_uid, float* __restrict__ out)
{
    __shared__ __align__(16) float lds[LDS_FLOATS];
    __shared__ float red[4];
    const int tid = threadIdx.x;
    const int bm0 = blockIdx.x * BM;   // row block (16)
    const int bi0 = blockIdx.y * BN;   // item block (782)

    // ---- stage sel tile k-major: selT[k][r], r in 0..63
    {
        const int k4 = tid & 15;   // k-chunk 0..15 (4 k's each)
        const int r0 = tid >> 4;   // 0..15
        #pragma unroll
        for (int it = 0; it < 4; ++it) {
            const int r = r0 + 16 * it;
            const int uid = center_uid[bm0 + r];
            const float4 v = *reinterpret_cast<const float4*>(
                user_emb + (size_t)uid * K_DIM + k4 * 4);
            float* p = &lds[SEL_OFF + (k4 * 4) * BMP + r];
            p[0 * BMP] = v.x; p[1 * BMP] = v.y; p[2 * BMP] = v.z; p[3 * BMP] = v.w;
        }
    }
    // ---- stage item tile k-major: itemT[k][i], i in 0..127 (zero-fill OOB)
    {
        const int k4 = tid & 15;
        const int i0 = tid >> 4;
        #pragma unroll
        for (int it = 0; it < 8; ++it) {
            const int i = i0 + 16 * it;
            const int gi = bi0 + i;
            float4 v = make_float4(0.f, 0.f, 0.f, 0.f);
            if (gi < N_DIM)
                v = *reinterpret_cast<const float4*>(
                    item_emb + (size_t)gi * K_DIM + k4 * 4);
            float* p = &lds[ITEM_OFF + (k4 * 4) * BNP + i];
            p[0 * BNP] = v.x; p[1 * BNP] = v.y; p[2 * BNP] = v.z; p[3 * BNP] = v.w;
        }
    }
    __syncthreads();

    const int tx = tid & 31;  // item lane (cols tx + 32c)
    const int ty = tid >> 5;  // row group (rows ty*8 + r)

    float acc[8][4];
    #pragma unroll
    for (int r = 0; r < 8; ++r)
        #pragma unroll
        for (int c = 0; c < 4; ++c) acc[r][c] = 0.f;

    const float* aBase = &lds[SEL_OFF + ty * 8];
    const float* bBase = &lds[ITEM_OFF + tx];

    #pragma unroll 8
    for (int k = 0; k < K_DIM; ++k) {
        const float4 a01 = *reinterpret_cast<const float4*>(aBase + k * BMP);
        const float4 a23 = *reinterpret_cast<const float4*>(aBase + k * BMP + 4);
        float b[4];
        #pragma unroll
        for (int c = 0; c < 4; ++c) b[c] = bBase[k * BNP + 32 * c];
        const float a[8] = {a01.x, a01.y, a01.z, a01.w, a23.x, a23.y, a23.z, a23.w};
        #pragma unroll
        for (int r = 0; r < 8; ++r)
            #pragma unroll
            for (int c = 0; c < 4; ++c)
                acc[r][c] = fmaf(a[r], b[c], acc[r][c]);
    }

    // ---- epilogue: store pref (out+1, 4B-aligned only -> scalar dword
    // stores, contiguous across 32 lanes) and accumulate sum(s^2)
    float ss = 0.f;
    float* pref = out + 1;
    #pragma unroll
    for (int r = 0; r < 8; ++r) {
        const size_t row = (size_t)(bm0 + ty * 8 + r) * N_DIM;
        #pragma unroll
        for (int c = 0; c < 4; ++c) {
            const int col = bi0 + tx + 32 * c;
            if (col < N_DIM) {
                const float v = acc[r][c];
                pref[row + col] = v;
                ss = fmaf(v, v, ss);
            }
        }
    }
    #pragma unroll
    for (int off = 32; off > 0; off >>= 1) ss += __shfl_xor(ss, off, 64);
    if ((tid & 63) == 0) red[tid >> 6] = ss;
    __syncthreads();
    if (tid == 0)
        atomicAdd(out, red[0] + red[1] + red[2] + red[3]);
}

// Positive-term correction: loss += sum over UNIQUE seq entries of (1 - 2s).
// One wave per batch row; K=64 == wave size: lane k holds dim k.
__global__ __launch_bounds__(64) void pos_kernel(
    const float* __restrict__ user_emb, const float* __restrict__ item_emb,
    const int* __restrict__ center_uid, const int* __restrict__ seq,
    float* __restrict__ out)
{
    const int b = blockIdx.x;
    const int lane = threadIdx.x;
    const int sv = (lane < HIST) ? seq[b * HIST + lane] : -1;
    const int uid = center_uid[b];
    const float selv = user_emb[(size_t)uid * K_DIM + lane];
    float corr = 0.f;
    for (int h = 0; h < HIST; ++h) {
        const int i = __shfl(sv, h, 64);
        const unsigned long long dup = __ballot(lane < h && sv == i);
        if (dup == 0ull) {  // first occurrence only (mask sets once)
            float p = selv * item_emb[(size_t)i * K_DIM + lane];
            #pragma unroll
            for (int off = 32; off > 0; off >>= 1) p += __shfl_xor(p, off, 64);
            if (lane == 0) corr += 1.f - 2.f * p;
        }
    }
    if (lane == 0) atomicAdd(out, corr);
}

extern "C" void kernel_launch(void* const* d_in, const int* in_sizes, int n_in,
                              void* d_out, int out_size, void* d_ws, size_t ws_size,
                              hipStream_t stream) {
    const float* user_emb  = (const float*)d_in[0];
    const float* item_emb  = (const float*)d_in[1];
    const int*   center_uid = (const int*)d_in[2];
    const int*   seq        = (const int*)d_in[3];
    float* out = (float*)d_out;

    // out[0] accumulates loss via atomics; pref fully overwritten by GEMM.
    hipMemsetAsync(out, 0, sizeof(float), stream);
    pos_kernel<<<dim3(M_DIM), dim3(64), 0, stream>>>(
        user_emb, item_emb, center_uid, seq, out);
    dim3 grid(M_DIM / BM, (N_DIM + BN - 1) / BN);
    gemm_loss_kernel<<<grid, dim3(256), 0, stream>>>(
        user_emb, item_emb, center_uid, out);
}